// Round 7
// baseline (44.680 us; speedup 1.0000x reference)
//
#include <hip/hip_runtime.h>
#include <hip/hip_bf16.h>

// Problem constants (from reference setup_inputs)
#define B_   8
#define T_   4096
#define D_   1024
#define DENT 256
#define F_   1280          // D_ + DENT
#define E_   32            // MAX_EVENTS
#define TVOCAB 512
#define THRB 0x40000000u   // __float_as_uint(2.0f); m>=0 so bit-compare == float-compare

// ---------------------------------------------------------------------------
// Kernel 1: event selection. One block per batch, 1024 threads.
// Keys in registers (4/thread); radix-select (4x8-bit, per-wave private
// histograms); ties -> smallest index (exact lax.top_k). Output sorted by time.
// (proven ~4us in rounds 4/5; unchanged except ws_cnt removal)
// ---------------------------------------------------------------------------
__global__ __launch_bounds__(1024) void k_select(
    const float* __restrict__ z,
    int* __restrict__ ws_times, int* __restrict__ ws_valid,
    float* __restrict__ out_valid, float* __restrict__ out_times)
{
    __shared__ unsigned s_hist[16 * 257];
    __shared__ unsigned s_tot[256];
    __shared__ int s_cnt, s_nsel;
    __shared__ int s_bbin; __shared__ unsigned s_bcg;
    __shared__ int s_selt[E_], s_sorted[E_];
    __shared__ int s_red[16];
    __shared__ int s_prev;

    const int tid  = threadIdx.x;
    const int b    = blockIdx.x;
    const int lane = tid & 63;
    const int wid  = tid >> 6;

    if (tid == 0) { s_cnt = 0; s_nsel = 0; }
    __syncthreads();

    unsigned key[4];
    int cnt = 0;
    const float* zb = z + (size_t)b * T_ * 8;
    #pragma unroll
    for (int j = 0; j < 4; ++j) {
        const int t = tid + j * 1024;
        const float* zp = zb + (size_t)t * 8;
        float4 z0 = *(const float4*)(zp);
        float4 z1 = *(const float4*)(zp + 4);
        float m = fmaxf(fmaxf(fmaxf(fabsf(z0.x), fabsf(z0.y)),
                              fmaxf(fabsf(z0.z), fabsf(z0.w))),
                        fmaxf(fmaxf(fabsf(z1.x), fabsf(z1.y)),
                              fmaxf(fabsf(z1.z), fabsf(z1.w))));
        key[j] = __float_as_uint(m);
        if (key[j] > THRB) cnt++;
    }
    #pragma unroll
    for (int off = 32; off > 0; off >>= 1) cnt += __shfl_down(cnt, off);
    if (lane == 0) atomicAdd(&s_cnt, cnt);
    __syncthreads();

    const int  n_ev = s_cnt;
    const bool fb   = (n_ev < 4);
    const int  V    = fb ? E_ : (n_ev < E_ ? n_ev : E_);

    if (!fb && n_ev <= E_) {
        #pragma unroll
        for (int j = 0; j < 4; ++j)
            if (key[j] > THRB) { int p = atomicAdd(&s_nsel, 1); s_selt[p] = tid + j * 1024; }
        __syncthreads();
    } else {
        unsigned prefix = 0;
        int need = E_;
        for (int p = 0; p < 4; ++p) {
            const int shift = 24 - 8 * p;
            for (int i = tid; i < 16 * 257; i += 1024) s_hist[i] = 0;
            __syncthreads();
            unsigned* h = s_hist + wid * 257;
            #pragma unroll
            for (int j = 0; j < 4; ++j) {
                bool elig = fb || (key[j] > THRB);
                if (elig && (p == 0 || (key[j] >> (shift + 8)) == prefix))
                    atomicAdd(&h[(key[j] >> shift) & 255u], 1u);
            }
            __syncthreads();
            if (tid < 256) {
                unsigned s = 0;
                #pragma unroll
                for (int w = 0; w < 16; ++w) s += s_hist[w * 257 + tid];
                s_tot[tid] = s;
            }
            __syncthreads();
            if (tid < 64) {
                unsigned b0 = s_tot[4*tid+0], b1 = s_tot[4*tid+1];
                unsigned b2 = s_tot[4*tid+2], b3 = s_tot[4*tid+3];
                unsigned lsum = b0 + b1 + b2 + b3;
                unsigned suf = lsum;
                #pragma unroll
                for (int off = 1; off < 64; off <<= 1) {
                    unsigned o = __shfl_down(suf, off);
                    if (tid + off < 64) suf += o;
                }
                unsigned excl = suf - lsum;
                unsigned cg3 = excl;
                unsigned cg2 = cg3 + b3;
                unsigned cg1 = cg2 + b2;
                unsigned cg0 = cg1 + b1;
                unsigned un  = (unsigned)need;
                if (cg3 < un && cg3 + b3 >= un) { s_bbin = 4*tid+3; s_bcg = cg3; }
                if (cg2 < un && cg2 + b2 >= un) { s_bbin = 4*tid+2; s_bcg = cg2; }
                if (cg1 < un && cg1 + b1 >= un) { s_bbin = 4*tid+1; s_bcg = cg1; }
                if (cg0 < un && cg0 + b0 >= un) { s_bbin = 4*tid+0; s_bcg = cg0; }
            }
            __syncthreads();
            need  -= (int)s_bcg;
            prefix = (prefix << 8) | (unsigned)s_bbin;
            __syncthreads();
        }
        const unsigned vstar   = prefix;
        const int      need_eq = need;

        #pragma unroll
        for (int j = 0; j < 4; ++j) {
            bool elig = fb || (key[j] > THRB);
            if (elig && key[j] > vstar) { int p = atomicAdd(&s_nsel, 1); s_selt[p] = tid + j * 1024; }
        }
        __syncthreads();
        int prev = -1;
        const int base = s_nsel;
        for (int q = 0; q < need_eq; ++q) {
            int best = 0x7fffffff;
            #pragma unroll
            for (int j = 0; j < 4; ++j) {
                bool elig = fb || (key[j] > THRB);
                int  t    = tid + j * 1024;
                if (elig && key[j] == vstar && t > prev && t < best) best = t;
            }
            #pragma unroll
            for (int off = 32; off > 0; off >>= 1) {
                int o = __shfl_down(best, off);
                if (o < best) best = o;
            }
            if (lane == 0) s_red[wid] = best;
            __syncthreads();
            if (tid == 0) {
                int m = s_red[0];
                #pragma unroll
                for (int w = 1; w < 16; ++w) if (s_red[w] < m) m = s_red[w];
                s_selt[base + q] = m;
                s_prev = m;
            }
            __syncthreads();
            prev = s_prev;
        }
    }

    if (tid < V) {
        int ti = s_selt[tid];
        int rank = 0;
        for (int j = 0; j < V; ++j) rank += (s_selt[j] < ti);
        s_sorted[rank] = ti;
    }
    __syncthreads();
    if (tid < E_) {
        int valid = (tid < V) ? 1 : 0;
        int t     = valid ? s_sorted[tid] : 0;
        ws_times[b * E_ + tid]  = t;
        ws_valid[b * E_ + tid]  = valid;
        out_times[b * E_ + tid] = (float)t;
        out_valid[b * E_ + tid] = (float)valid;
    }
}

// ---------------------------------------------------------------------------
// Kernel 2: single-kernel GEMM, latency-amortized.
// Grid 256 blocks (8 row-tiles x 32 col-tiles), tile 32x32, FULL K=1280 as
// 10 iters of BK=128. No split-K, no fences, no partials.
// Per iter: per-wave compute ~2.5K cyc >> HBM latency; next-tile global
// loads are issued into registers BEFORE the compute phase.
// LDS row-major [32][132] (pad keeps f4 16B-aligned); microtile rows
// {tr,tr+16} x cols {tc,tc+16} -> 2-way bank aliasing (free).
// ---------------------------------------------------------------------------
#define BK   128
#define LDP  132           // row pitch in floats (132*4 % 16 == 0)
#define NIT  (F_ / BK)     // 10

__global__ __launch_bounds__(256, 4) void k_gemm(
    const float* __restrict__ h_seq, const float* __restrict__ ent,
    const float* __restrict__ W, const float* __restrict__ bias,
    const float* __restrict__ temb,
    const int* __restrict__ ws_times, const int* __restrict__ ws_valid,
    float* __restrict__ out)
{
    __shared__ float As[32][LDP];
    __shared__ float Bs[32][LDP];

    const int tid = threadIdx.x;
    // XCD-aware swizzle: XCD k gets col-tiles [4k..4k+3] x all row-tiles.
    // Per-XCD footprint: W panel 640KB + A 1.25MB -> L2-resident.
    const int flat  = blockIdx.x;          // 0..255
    const int xcd   = flat & 7;
    const int i     = flat >> 3;           // 0..31
    const int combo = xcd * 32 + i;        // 0..255
    const int yc    = combo >> 3;          // col tile 0..31
    const int xr    = combo & 7;           // row tile 0..7

    const int row0 = xr * 32;
    const int col0 = yc * 32;

    // ---- loader setup: each thread loads 4 float4 for A and 4 for B ----
    const int lrow = tid >> 3;             // 0..31 (A row / B col within tile)
    const int lfo  = (tid & 7) * 4;        // float offset 0..28 within 32-float chunk
    size_t a_baseh, a_basee, b_base;
    float  a_v;
    {
        int grow = row0 + lrow;
        int t    = ws_times[grow];
        a_v      = (float)ws_valid[grow];
        int bb   = grow >> 5;
        a_baseh  = ((size_t)bb * T_ + t) * D_   + lfo;
        a_basee  = ((size_t)bb * T_ + t) * DENT + lfo;
        b_base   = (size_t)(col0 + lrow) * F_ + lfo;
    }

    const int tr = tid >> 4;   // 0..15 -> rows {tr, tr+16}
    const int tc = tid & 15;   // 0..15 -> cols {tc, tc+16}

    float4 ra[4], rb[4];
    float acc00 = 0.f, acc01 = 0.f, acc10 = 0.f, acc11 = 0.f;

#define LOAD_TILE(KC) do {                                                   \
    const int fb0 = (KC) * BK;                                               \
    const float* asrc; size_t abase;                                         \
    if (fb0 < D_) { asrc = h_seq; abase = a_baseh + fb0; }                   \
    else          { asrc = ent;   abase = a_basee + (fb0 - D_); }            \
    _Pragma("unroll")                                                        \
    for (int j = 0; j < 4; ++j) {                                            \
        ra[j] = *(const float4*)(asrc + abase + j * 32);                     \
        rb[j] = *(const float4*)(W + b_base + fb0 + j * 32);                 \
    } } while (0)

    LOAD_TILE(0);

    for (int kc = 0; kc < NIT; ++kc) {
        __syncthreads();   // LDS free (previous compute done)
        #pragma unroll
        for (int j = 0; j < 4; ++j) {
            float4 av = ra[j];
            av.x *= a_v; av.y *= a_v; av.z *= a_v; av.w *= a_v;
            *(float4*)&As[lrow][lfo + j * 32] = av;
            *(float4*)&Bs[lrow][lfo + j * 32] = rb[j];
        }
        __syncthreads();

        if (kc < NIT - 1) LOAD_TILE(kc + 1);   // issue next tile NOW

        #pragma unroll
        for (int g = 0; g < BK / 4; ++g) {
            const float4 a0 = *(const float4*)&As[tr     ][g * 4];
            const float4 a1 = *(const float4*)&As[tr + 16][g * 4];
            const float4 b0 = *(const float4*)&Bs[tc     ][g * 4];
            const float4 b1 = *(const float4*)&Bs[tc + 16][g * 4];
            acc00 = fmaf(a0.x, b0.x, acc00); acc00 = fmaf(a0.y, b0.y, acc00);
            acc00 = fmaf(a0.z, b0.z, acc00); acc00 = fmaf(a0.w, b0.w, acc00);
            acc01 = fmaf(a0.x, b1.x, acc01); acc01 = fmaf(a0.y, b1.y, acc01);
            acc01 = fmaf(a0.z, b1.z, acc01); acc01 = fmaf(a0.w, b1.w, acc01);
            acc10 = fmaf(a1.x, b0.x, acc10); acc10 = fmaf(a1.y, b0.y, acc10);
            acc10 = fmaf(a1.z, b0.z, acc10); acc10 = fmaf(a1.w, b0.w, acc10);
            acc11 = fmaf(a1.x, b1.x, acc11); acc11 = fmaf(a1.y, b1.y, acc11);
            acc11 = fmaf(a1.z, b1.z, acc11); acc11 = fmaf(a1.w, b1.w, acc11);
        }
    }
#undef LOAD_TILE

    // ---- epilogue: + bias + time_embed[clip(t)] ----
    const int c0 = col0 + tc;
    const int c1 = col0 + tc + 16;
    const float bi0 = bias[c0], bi1 = bias[c1];
    {
        int grow = row0 + tr;
        int t    = ws_times[grow];
        int tcl  = t < (TVOCAB - 1) ? t : (TVOCAB - 1);
        const float* te = temb + (size_t)tcl * D_;
        out[(size_t)grow * D_ + c0] = acc00 + bi0 + te[c0];
        out[(size_t)grow * D_ + c1] = acc01 + bi1 + te[c1];
    }
    {
        int grow = row0 + tr + 16;
        int t    = ws_times[grow];
        int tcl  = t < (TVOCAB - 1) ? t : (TVOCAB - 1);
        const float* te = temb + (size_t)tcl * D_;
        out[(size_t)grow * D_ + c0] = acc10 + bi0 + te[c0];
        out[(size_t)grow * D_ + c1] = acc11 + bi1 + te[c1];
    }
}

// ---------------------------------------------------------------------------
extern "C" void kernel_launch(void* const* d_in, const int* in_sizes, int n_in,
                              void* d_out, int out_size, void* d_ws, size_t ws_size,
                              hipStream_t stream)
{
    const float* h_seq = (const float*)d_in[0];
    const float* z     = (const float*)d_in[1];
    const float* ent   = (const float*)d_in[2];
    const float* W     = (const float*)d_in[3];
    const float* bias  = (const float*)d_in[4];
    const float* temb  = (const float*)d_in[5];

    float* out       = (float*)d_out;
    float* out_tape  = out;                                // 262144
    float* out_valid = out + (size_t)B_ * E_ * D_;         // 256
    float* out_times = out_valid + B_ * E_;                // 256

    // ws layout: [0] times (256 int) | [1KB] valid (256 int)
    int* ws_times = (int*)d_ws;
    int* ws_valid = (int*)((char*)d_ws + 1024);

    k_select<<<B_, 1024, 0, stream>>>(z, ws_times, ws_valid,
                                      out_valid, out_times);

    k_gemm<<<256, 256, 0, stream>>>(h_seq, ent, W, bias, temb,
                                    ws_times, ws_valid, out_tape);
}

// Round 8
// 37.355 us; speedup vs baseline: 1.1961x; 1.1961x over previous
//
#include <hip/hip_runtime.h>
#include <hip/hip_bf16.h>

// Problem constants (from reference setup_inputs)
#define B_   8
#define T_   4096
#define D_   1024
#define DENT 256
#define F_   1280          // D_ + DENT
#define E_   32            // MAX_EVENTS
#define TVOCAB 512
#define THRB 0x40000000u   // __float_as_uint(2.0f); m>=0 so bit-compare == float-compare

// ---------------------------------------------------------------------------
// Kernel 1: event selection. One block per batch, 1024 threads.
// Keys in registers (4/thread); radix-select (4x8-bit, per-wave private
// histograms); ties -> smallest index (exact lax.top_k). Output sorted by time.
// (proven in rounds 4-7; unchanged)
// ---------------------------------------------------------------------------
__global__ __launch_bounds__(1024) void k_select(
    const float* __restrict__ z,
    int* __restrict__ ws_times, int* __restrict__ ws_valid,
    float* __restrict__ out_valid, float* __restrict__ out_times)
{
    __shared__ unsigned s_hist[16 * 257];
    __shared__ unsigned s_tot[256];
    __shared__ int s_cnt, s_nsel;
    __shared__ int s_bbin; __shared__ unsigned s_bcg;
    __shared__ int s_selt[E_], s_sorted[E_];
    __shared__ int s_red[16];
    __shared__ int s_prev;

    const int tid  = threadIdx.x;
    const int b    = blockIdx.x;
    const int lane = tid & 63;
    const int wid  = tid >> 6;

    if (tid == 0) { s_cnt = 0; s_nsel = 0; }
    __syncthreads();

    unsigned key[4];
    int cnt = 0;
    const float* zb = z + (size_t)b * T_ * 8;
    #pragma unroll
    for (int j = 0; j < 4; ++j) {
        const int t = tid + j * 1024;
        const float* zp = zb + (size_t)t * 8;
        float4 z0 = *(const float4*)(zp);
        float4 z1 = *(const float4*)(zp + 4);
        float m = fmaxf(fmaxf(fmaxf(fabsf(z0.x), fabsf(z0.y)),
                              fmaxf(fabsf(z0.z), fabsf(z0.w))),
                        fmaxf(fmaxf(fabsf(z1.x), fabsf(z1.y)),
                              fmaxf(fabsf(z1.z), fabsf(z1.w))));
        key[j] = __float_as_uint(m);
        if (key[j] > THRB) cnt++;
    }
    #pragma unroll
    for (int off = 32; off > 0; off >>= 1) cnt += __shfl_down(cnt, off);
    if (lane == 0) atomicAdd(&s_cnt, cnt);
    __syncthreads();

    const int  n_ev = s_cnt;
    const bool fb   = (n_ev < 4);
    const int  V    = fb ? E_ : (n_ev < E_ ? n_ev : E_);

    if (!fb && n_ev <= E_) {
        #pragma unroll
        for (int j = 0; j < 4; ++j)
            if (key[j] > THRB) { int p = atomicAdd(&s_nsel, 1); s_selt[p] = tid + j * 1024; }
        __syncthreads();
    } else {
        unsigned prefix = 0;
        int need = E_;
        for (int p = 0; p < 4; ++p) {
            const int shift = 24 - 8 * p;
            for (int i = tid; i < 16 * 257; i += 1024) s_hist[i] = 0;
            __syncthreads();
            unsigned* h = s_hist + wid * 257;
            #pragma unroll
            for (int j = 0; j < 4; ++j) {
                bool elig = fb || (key[j] > THRB);
                if (elig && (p == 0 || (key[j] >> (shift + 8)) == prefix))
                    atomicAdd(&h[(key[j] >> shift) & 255u], 1u);
            }
            __syncthreads();
            if (tid < 256) {
                unsigned s = 0;
                #pragma unroll
                for (int w = 0; w < 16; ++w) s += s_hist[w * 257 + tid];
                s_tot[tid] = s;
            }
            __syncthreads();
            if (tid < 64) {
                unsigned b0 = s_tot[4*tid+0], b1 = s_tot[4*tid+1];
                unsigned b2 = s_tot[4*tid+2], b3 = s_tot[4*tid+3];
                unsigned lsum = b0 + b1 + b2 + b3;
                unsigned suf = lsum;
                #pragma unroll
                for (int off = 1; off < 64; off <<= 1) {
                    unsigned o = __shfl_down(suf, off);
                    if (tid + off < 64) suf += o;
                }
                unsigned excl = suf - lsum;
                unsigned cg3 = excl;
                unsigned cg2 = cg3 + b3;
                unsigned cg1 = cg2 + b2;
                unsigned cg0 = cg1 + b1;
                unsigned un  = (unsigned)need;
                if (cg3 < un && cg3 + b3 >= un) { s_bbin = 4*tid+3; s_bcg = cg3; }
                if (cg2 < un && cg2 + b2 >= un) { s_bbin = 4*tid+2; s_bcg = cg2; }
                if (cg1 < un && cg1 + b1 >= un) { s_bbin = 4*tid+1; s_bcg = cg1; }
                if (cg0 < un && cg0 + b0 >= un) { s_bbin = 4*tid+0; s_bcg = cg0; }
            }
            __syncthreads();
            need  -= (int)s_bcg;
            prefix = (prefix << 8) | (unsigned)s_bbin;
            __syncthreads();
        }
        const unsigned vstar   = prefix;
        const int      need_eq = need;

        #pragma unroll
        for (int j = 0; j < 4; ++j) {
            bool elig = fb || (key[j] > THRB);
            if (elig && key[j] > vstar) { int p = atomicAdd(&s_nsel, 1); s_selt[p] = tid + j * 1024; }
        }
        __syncthreads();
        int prev = -1;
        const int base = s_nsel;
        for (int q = 0; q < need_eq; ++q) {
            int best = 0x7fffffff;
            #pragma unroll
            for (int j = 0; j < 4; ++j) {
                bool elig = fb || (key[j] > THRB);
                int  t    = tid + j * 1024;
                if (elig && key[j] == vstar && t > prev && t < best) best = t;
            }
            #pragma unroll
            for (int off = 32; off > 0; off >>= 1) {
                int o = __shfl_down(best, off);
                if (o < best) best = o;
            }
            if (lane == 0) s_red[wid] = best;
            __syncthreads();
            if (tid == 0) {
                int m = s_red[0];
                #pragma unroll
                for (int w = 1; w < 16; ++w) if (s_red[w] < m) m = s_red[w];
                s_selt[base + q] = m;
                s_prev = m;
            }
            __syncthreads();
            prev = s_prev;
        }
    }

    if (tid < V) {
        int ti = s_selt[tid];
        int rank = 0;
        for (int j = 0; j < V; ++j) rank += (s_selt[j] < ti);
        s_sorted[rank] = ti;
    }
    __syncthreads();
    if (tid < E_) {
        int valid = (tid < V) ? 1 : 0;
        int t     = valid ? s_sorted[tid] : 0;
        ws_times[b * E_ + tid]  = t;
        ws_valid[b * E_ + tid]  = valid;
        out_times[b * E_ + tid] = (float)t;
        out_valid[b * E_ + tid] = (float)valid;
    }
}

// ---------------------------------------------------------------------------
// Kernel 2: single-kernel GEMM, LDS-bandwidth-optimized.
// Grid 256 blocks (8 row-tiles x 32 col-tiles), tile 32x32, K=1280 as
// 10 iters of BK=128 (R7 skeleton: reg-prefetch of next tile, 2 barriers/iter).
// NEW: each wave computes the full 32x32 tile over 1/4 of the k-groups
// (g = w mod 4 interleave) with a 4x4 microtile -> 0.5 FMA per LDS byte
// (2x round 7). Rows/cols grouped stride-8 so every ds_read_b128 hits 8
// distinct 16B slots = all 32 banks (conflict-free). Wave partials reduced
// via LDS at the end + fused bias/time_embed epilogue.
// ---------------------------------------------------------------------------
#define BK   128
#define LDP  132           // row pitch in floats; f4-aligned, bank-spread
#define NIT  (F_ / BK)     // 10

__global__ __launch_bounds__(256) void k_gemm(
    const float* __restrict__ h_seq, const float* __restrict__ ent,
    const float* __restrict__ W, const float* __restrict__ bias,
    const float* __restrict__ temb,
    const int* __restrict__ ws_times, const int* __restrict__ ws_valid,
    float* __restrict__ out)
{
    __shared__ float As[32][LDP];
    __shared__ float Bs[32][LDP];
    __shared__ float Red[4][32][36];   // per-wave partials for final reduce

    const int tid = threadIdx.x;
    // XCD-aware swizzle: XCD k gets col-tiles [4k..4k+3] x all row-tiles.
    const int flat  = blockIdx.x;          // 0..255
    const int xcd   = flat & 7;
    const int i     = flat >> 3;           // 0..31
    const int combo = xcd * 32 + i;        // 0..255
    const int yc    = combo >> 3;          // col tile 0..31
    const int xr    = combo & 7;           // row tile 0..7

    const int row0 = xr * 32;
    const int col0 = yc * 32;

    // ---- loader setup (identical to round 7): 4 float4 A + 4 float4 B ----
    const int lrow = tid >> 3;             // 0..31 (A row / B col within tile)
    const int lfo  = (tid & 7) * 4;        // 0..28
    size_t a_baseh, a_basee, b_base;
    float  a_v;
    {
        int grow = row0 + lrow;
        int t    = ws_times[grow];
        a_v      = (float)ws_valid[grow];
        int bb   = grow >> 5;
        a_baseh  = ((size_t)bb * T_ + t) * D_   + lfo;
        a_basee  = ((size_t)bb * T_ + t) * DENT + lfo;
        b_base   = (size_t)(col0 + lrow) * F_ + lfo;
    }

    const int lane = tid & 63;
    const int wv   = tid >> 6;   // wave 0..3  -> k-groups g = wv + 4*gi
    const int rg   = lane >> 3;  // 0..7 -> rows {rg, rg+8, rg+16, rg+24}
    const int cg   = lane & 7;   // 0..7 -> cols {cg, cg+8, cg+16, cg+24}

    float4 ra[4], rb[4];
    float acc[4][4] = {};        // [row j][col i] partial over this wave's k

#define LOAD_TILE(KC) do {                                                   \
    const int fb0 = (KC) * BK;                                               \
    const float* asrc; size_t abase;                                         \
    if (fb0 < D_) { asrc = h_seq; abase = a_baseh + fb0; }                   \
    else          { asrc = ent;   abase = a_basee + (fb0 - D_); }            \
    _Pragma("unroll")                                                        \
    for (int j = 0; j < 4; ++j) {                                            \
        ra[j] = *(const float4*)(asrc + abase + j * 32);                     \
        rb[j] = *(const float4*)(W + b_base + fb0 + j * 32);                 \
    } } while (0)

    LOAD_TILE(0);

    for (int kc = 0; kc < NIT; ++kc) {
        __syncthreads();   // previous compute done reading LDS
        #pragma unroll
        for (int j = 0; j < 4; ++j) {
            float4 av = ra[j];
            av.x *= a_v; av.y *= a_v; av.z *= a_v; av.w *= a_v;
            *(float4*)&As[lrow][lfo + j * 32] = av;
            *(float4*)&Bs[lrow][lfo + j * 32] = rb[j];
        }
        __syncthreads();

        if (kc < NIT - 1) LOAD_TILE(kc + 1);   // issue next tile NOW

        // this wave covers g = wv, wv+4, ..., wv+28 (8 of 32 k-groups)
        #pragma unroll
        for (int gi = 0; gi < 8; ++gi) {
            const int k4 = (wv + gi * 4) * 4;
            float4 a0 = *(const float4*)&As[rg     ][k4];
            float4 a1 = *(const float4*)&As[rg +  8][k4];
            float4 a2 = *(const float4*)&As[rg + 16][k4];
            float4 a3 = *(const float4*)&As[rg + 24][k4];
            float4 b0 = *(const float4*)&Bs[cg     ][k4];
            float4 b1 = *(const float4*)&Bs[cg +  8][k4];
            float4 b2 = *(const float4*)&Bs[cg + 16][k4];
            float4 b3 = *(const float4*)&Bs[cg + 24][k4];
            #define DOT4(A_, J_) do {                                        \
                acc[J_][0] = fmaf(A_.x, b0.x, acc[J_][0]);                   \
                acc[J_][0] = fmaf(A_.y, b0.y, acc[J_][0]);                   \
                acc[J_][0] = fmaf(A_.z, b0.z, acc[J_][0]);                   \
                acc[J_][0] = fmaf(A_.w, b0.w, acc[J_][0]);                   \
                acc[J_][1] = fmaf(A_.x, b1.x, acc[J_][1]);                   \
                acc[J_][1] = fmaf(A_.y, b1.y, acc[J_][1]);                   \
                acc[J_][1] = fmaf(A_.z, b1.z, acc[J_][1]);                   \
                acc[J_][1] = fmaf(A_.w, b1.w, acc[J_][1]);                   \
                acc[J_][2] = fmaf(A_.x, b2.x, acc[J_][2]);                   \
                acc[J_][2] = fmaf(A_.y, b2.y, acc[J_][2]);                   \
                acc[J_][2] = fmaf(A_.z, b2.z, acc[J_][2]);                   \
                acc[J_][2] = fmaf(A_.w, b2.w, acc[J_][2]);                   \
                acc[J_][3] = fmaf(A_.x, b3.x, acc[J_][3]);                   \
                acc[J_][3] = fmaf(A_.y, b3.y, acc[J_][3]);                   \
                acc[J_][3] = fmaf(A_.z, b3.z, acc[J_][3]);                   \
                acc[J_][3] = fmaf(A_.w, b3.w, acc[J_][3]);                   \
            } while (0)
            DOT4(a0, 0); DOT4(a1, 1); DOT4(a2, 2); DOT4(a3, 3);
            #undef DOT4
        }
    }
#undef LOAD_TILE

    // ---- cross-wave k-reduction via LDS ----
    __syncthreads();
    #pragma unroll
    for (int j = 0; j < 4; ++j)
        #pragma unroll
        for (int i2 = 0; i2 < 4; ++i2)
            Red[wv][rg + 8 * j][cg + 8 * i2] = acc[j][i2];
    __syncthreads();

    // ---- epilogue: sum 4 wave-partials + bias + time_embed, f4 store ----
    {
        const int r  = tid >> 3;            // 0..31
        const int c0 = (tid & 7) * 4;       // 0..28
        float4 s0 = *(const float4*)&Red[0][r][c0];
        float4 s1 = *(const float4*)&Red[1][r][c0];
        float4 s2 = *(const float4*)&Red[2][r][c0];
        float4 s3 = *(const float4*)&Red[3][r][c0];
        float4 s;
        s.x = (s0.x + s1.x) + (s2.x + s3.x);
        s.y = (s0.y + s1.y) + (s2.y + s3.y);
        s.z = (s0.z + s1.z) + (s2.z + s3.z);
        s.w = (s0.w + s1.w) + (s2.w + s3.w);
        const int grow = row0 + r;
        const int cb   = col0 + c0;
        int t   = ws_times[grow];
        int tcl = t < (TVOCAB - 1) ? t : (TVOCAB - 1);
        const float4 bi = *(const float4*)(bias + cb);
        const float4 te = *(const float4*)(temb + (size_t)tcl * D_ + cb);
        s.x += bi.x + te.x; s.y += bi.y + te.y;
        s.z += bi.z + te.z; s.w += bi.w + te.w;
        *(float4*)(out + (size_t)grow * D_ + cb) = s;
    }
}

// ---------------------------------------------------------------------------
extern "C" void kernel_launch(void* const* d_in, const int* in_sizes, int n_in,
                              void* d_out, int out_size, void* d_ws, size_t ws_size,
                              hipStream_t stream)
{
    const float* h_seq = (const float*)d_in[0];
    const float* z     = (const float*)d_in[1];
    const float* ent   = (const float*)d_in[2];
    const float* W     = (const float*)d_in[3];
    const float* bias  = (const float*)d_in[4];
    const float* temb  = (const float*)d_in[5];

    float* out       = (float*)d_out;
    float* out_tape  = out;                                // 262144
    float* out_valid = out + (size_t)B_ * E_ * D_;         // 256
    float* out_times = out_valid + B_ * E_;                // 256

    // ws layout: [0] times (256 int) | [1KB] valid (256 int)
    int* ws_times = (int*)d_ws;
    int* ws_valid = (int*)((char*)d_ws + 1024);

    k_select<<<B_, 1024, 0, stream>>>(z, ws_times, ws_valid,
                                      out_valid, out_times);

    k_gemm<<<256, 256, 0, stream>>>(h_seq, ent, W, bias, temb,
                                    ws_times, ws_valid, out_tape);
}

// Round 9
// 21.811 us; speedup vs baseline: 2.0485x; 1.7126x over previous
//
#include <hip/hip_runtime.h>
#include <hip/hip_bf16.h>

// Problem constants (from reference setup_inputs)
#define B_   8
#define T_   4096
#define D_   1024
#define DENT 256
#define F_   1280          // D_ + DENT
#define E_   32            // MAX_EVENTS
#define TVOCAB 512
#define THRB 0x40000000u   // __float_as_uint(2.0f); m>=0 so bit-compare == float-compare

// ---------------------------------------------------------------------------
// Kernel 1: event selection. One block per batch, 1024 threads.
// (proven rounds 4-8; unchanged)
// ---------------------------------------------------------------------------
__global__ __launch_bounds__(1024) void k_select(
    const float* __restrict__ z,
    int* __restrict__ ws_times, int* __restrict__ ws_valid,
    float* __restrict__ out_valid, float* __restrict__ out_times)
{
    __shared__ unsigned s_hist[16 * 257];
    __shared__ unsigned s_tot[256];
    __shared__ int s_cnt, s_nsel;
    __shared__ int s_bbin; __shared__ unsigned s_bcg;
    __shared__ int s_selt[E_], s_sorted[E_];
    __shared__ int s_red[16];
    __shared__ int s_prev;

    const int tid  = threadIdx.x;
    const int b    = blockIdx.x;
    const int lane = tid & 63;
    const int wid  = tid >> 6;

    if (tid == 0) { s_cnt = 0; s_nsel = 0; }
    __syncthreads();

    unsigned key[4];
    int cnt = 0;
    const float* zb = z + (size_t)b * T_ * 8;
    #pragma unroll
    for (int j = 0; j < 4; ++j) {
        const int t = tid + j * 1024;
        const float* zp = zb + (size_t)t * 8;
        float4 z0 = *(const float4*)(zp);
        float4 z1 = *(const float4*)(zp + 4);
        float m = fmaxf(fmaxf(fmaxf(fabsf(z0.x), fabsf(z0.y)),
                              fmaxf(fabsf(z0.z), fabsf(z0.w))),
                        fmaxf(fmaxf(fabsf(z1.x), fabsf(z1.y)),
                              fmaxf(fabsf(z1.z), fabsf(z1.w))));
        key[j] = __float_as_uint(m);
        if (key[j] > THRB) cnt++;
    }
    #pragma unroll
    for (int off = 32; off > 0; off >>= 1) cnt += __shfl_down(cnt, off);
    if (lane == 0) atomicAdd(&s_cnt, cnt);
    __syncthreads();

    const int  n_ev = s_cnt;
    const bool fb   = (n_ev < 4);
    const int  V    = fb ? E_ : (n_ev < E_ ? n_ev : E_);

    if (!fb && n_ev <= E_) {
        #pragma unroll
        for (int j = 0; j < 4; ++j)
            if (key[j] > THRB) { int p = atomicAdd(&s_nsel, 1); s_selt[p] = tid + j * 1024; }
        __syncthreads();
    } else {
        unsigned prefix = 0;
        int need = E_;
        for (int p = 0; p < 4; ++p) {
            const int shift = 24 - 8 * p;
            for (int i = tid; i < 16 * 257; i += 1024) s_hist[i] = 0;
            __syncthreads();
            unsigned* h = s_hist + wid * 257;
            #pragma unroll
            for (int j = 0; j < 4; ++j) {
                bool elig = fb || (key[j] > THRB);
                if (elig && (p == 0 || (key[j] >> (shift + 8)) == prefix))
                    atomicAdd(&h[(key[j] >> shift) & 255u], 1u);
            }
            __syncthreads();
            if (tid < 256) {
                unsigned s = 0;
                #pragma unroll
                for (int w = 0; w < 16; ++w) s += s_hist[w * 257 + tid];
                s_tot[tid] = s;
            }
            __syncthreads();
            if (tid < 64) {
                unsigned b0 = s_tot[4*tid+0], b1 = s_tot[4*tid+1];
                unsigned b2 = s_tot[4*tid+2], b3 = s_tot[4*tid+3];
                unsigned lsum = b0 + b1 + b2 + b3;
                unsigned suf = lsum;
                #pragma unroll
                for (int off = 1; off < 64; off <<= 1) {
                    unsigned o = __shfl_down(suf, off);
                    if (tid + off < 64) suf += o;
                }
                unsigned excl = suf - lsum;
                unsigned cg3 = excl;
                unsigned cg2 = cg3 + b3;
                unsigned cg1 = cg2 + b2;
                unsigned cg0 = cg1 + b1;
                unsigned un  = (unsigned)need;
                if (cg3 < un && cg3 + b3 >= un) { s_bbin = 4*tid+3; s_bcg = cg3; }
                if (cg2 < un && cg2 + b2 >= un) { s_bbin = 4*tid+2; s_bcg = cg2; }
                if (cg1 < un && cg1 + b1 >= un) { s_bbin = 4*tid+1; s_bcg = cg1; }
                if (cg0 < un && cg0 + b0 >= un) { s_bbin = 4*tid+0; s_bcg = cg0; }
            }
            __syncthreads();
            need  -= (int)s_bcg;
            prefix = (prefix << 8) | (unsigned)s_bbin;
            __syncthreads();
        }
        const unsigned vstar   = prefix;
        const int      need_eq = need;

        #pragma unroll
        for (int j = 0; j < 4; ++j) {
            bool elig = fb || (key[j] > THRB);
            if (elig && key[j] > vstar) { int p = atomicAdd(&s_nsel, 1); s_selt[p] = tid + j * 1024; }
        }
        __syncthreads();
        int prev = -1;
        const int base = s_nsel;
        for (int q = 0; q < need_eq; ++q) {
            int best = 0x7fffffff;
            #pragma unroll
            for (int j = 0; j < 4; ++j) {
                bool elig = fb || (key[j] > THRB);
                int  t    = tid + j * 1024;
                if (elig && key[j] == vstar && t > prev && t < best) best = t;
            }
            #pragma unroll
            for (int off = 32; off > 0; off >>= 1) {
                int o = __shfl_down(best, off);
                if (o < best) best = o;
            }
            if (lane == 0) s_red[wid] = best;
            __syncthreads();
            if (tid == 0) {
                int m = s_red[0];
                #pragma unroll
                for (int w = 1; w < 16; ++w) if (s_red[w] < m) m = s_red[w];
                s_selt[base + q] = m;
                s_prev = m;
            }
            __syncthreads();
            prev = s_prev;
        }
    }

    if (tid < V) {
        int ti = s_selt[tid];
        int rank = 0;
        for (int j = 0; j < V; ++j) rank += (s_selt[j] < ti);
        s_sorted[rank] = ti;
    }
    __syncthreads();
    if (tid < E_) {
        int valid = (tid < V) ? 1 : 0;
        int t     = valid ? s_sorted[tid] : 0;
        ws_times[b * E_ + tid]  = t;
        ws_valid[b * E_ + tid]  = valid;
        out_times[b * E_ + tid] = (float)t;
        out_valid[b * E_ + tid] = (float)valid;
    }
}

// ---------------------------------------------------------------------------
// Kernel 2: MFMA GEMM (bf16 inputs, f32 accumulate).
// R8 skeleton: 256 blocks (8 row x 32 col tiles of 32x32), BK=128 staged per
// iter, 2 barriers/iter, XCD swizzle, per-wave k-quarter + LDS reduce.
// NEW: stage As/Bs as bf16 (RNE pack in the LDS write); each wave runs
// 2 x mfma_f32_32x32x16_bf16 per iter on its 32-k slice; 2-deep register
// prefetch hides HBM/L2 latency across a full iteration.
// Fragment layouts (HW-verified, learn_hip m74/m101):
//   A: lane l -> row l&31, k = (l>>5)*8 + j   (8 contiguous bf16 = 16B)
//   B: lane l -> col l&31, k = (l>>5)*8 + j
//   C/D: col = l&31, row = (r&3) + 8*(r>>2) + 4*(l>>5), r in [0,16)
// ---------------------------------------------------------------------------
#define BK   128
#define LDPB 136           // bf16 row pitch: 272B, 16B-aligned, ~2-way banks
#define NIT  (F_ / BK)     // 10

typedef short  bf16x8 __attribute__((ext_vector_type(8)));
typedef float  f32x16 __attribute__((ext_vector_type(16)));

// RNE f32 pair -> packed bf16x2 (lo in low half)
#define PKBF(x, y) \
    ( ((__float_as_uint(x) + 0x7FFFu + ((__float_as_uint(x) >> 16) & 1u)) >> 16) | \
      ((__float_as_uint(y) + 0x7FFFu + ((__float_as_uint(y) >> 16) & 1u)) & 0xFFFF0000u) )

__global__ __launch_bounds__(256) void k_gemm(
    const float* __restrict__ h_seq, const float* __restrict__ ent,
    const float* __restrict__ W, const float* __restrict__ bias,
    const float* __restrict__ temb,
    const int* __restrict__ ws_times, const int* __restrict__ ws_valid,
    float* __restrict__ out)
{
    __shared__ unsigned short As[32][LDPB];
    __shared__ unsigned short Bs[32][LDPB];
    __shared__ float Red[4][32][36];   // per-wave partials for final reduce

    const int tid = threadIdx.x;
    // XCD-aware swizzle: XCD k gets col-tiles [4k..4k+3] x all row-tiles.
    const int flat  = blockIdx.x;          // 0..255
    const int xcd   = flat & 7;
    const int i     = flat >> 3;           // 0..31
    const int combo = xcd * 32 + i;        // 0..255
    const int yc    = combo >> 3;          // col tile 0..31
    const int xr    = combo & 7;           // row tile 0..7

    const int row0 = xr * 32;
    const int col0 = yc * 32;

    // ---- loader setup (R8-identical): 4 float4 A + 4 float4 B per thread ----
    const int lrow = tid >> 3;             // 0..31 (A row / B col within tile)
    const int lfo  = (tid & 7) * 4;        // 0..28
    size_t a_baseh, a_basee, b_base;
    float  a_v;
    {
        int grow = row0 + lrow;
        int t    = ws_times[grow];
        a_v      = (float)ws_valid[grow];
        int bb   = grow >> 5;
        a_baseh  = ((size_t)bb * T_ + t) * D_   + lfo;
        a_basee  = ((size_t)bb * T_ + t) * DENT + lfo;
        b_base   = (size_t)(col0 + lrow) * F_ + lfo;
    }

    const int lane = tid & 63;
    const int wv   = tid >> 6;   // wave 0..3 -> k-slice [wv*32, wv*32+32)
    const int frow = lane & 31;  // A row / B col for fragments
    const int kq   = (lane >> 5) * 8;

    float4 ra0[4], rb0[4], ra1[4], rb1[4];
    f32x16 acc = {0,0,0,0,0,0,0,0,0,0,0,0,0,0,0,0};

#define LOAD_TILE(KC, RA, RB) do {                                           \
    const int fb0 = (KC) * BK;                                               \
    const float* asrc; size_t abase;                                         \
    if (fb0 < D_) { asrc = h_seq; abase = a_baseh + fb0; }                   \
    else          { asrc = ent;   abase = a_basee + (fb0 - D_); }            \
    _Pragma("unroll")                                                        \
    for (int j = 0; j < 4; ++j) {                                            \
        RA[j] = *(const float4*)(asrc + abase + j * 32);                     \
        RB[j] = *(const float4*)(W + b_base + fb0 + j * 32);                 \
    } } while (0)

#define STORE_TILE(RA, RB) do {                                              \
    _Pragma("unroll")                                                        \
    for (int j = 0; j < 4; ++j) {                                            \
        float4 av = RA[j];                                                   \
        av.x *= a_v; av.y *= a_v; av.z *= a_v; av.w *= a_v;                  \
        *(uint2*)&As[lrow][lfo + j * 32] =                                   \
            make_uint2(PKBF(av.x, av.y), PKBF(av.z, av.w));                  \
        float4 bv = RB[j];                                                   \
        *(uint2*)&Bs[lrow][lfo + j * 32] =                                   \
            make_uint2(PKBF(bv.x, bv.y), PKBF(bv.z, bv.w));                  \
    } } while (0)

#define COMPUTE() do {                                                       \
    const int ks0 = wv * 32;                                                 \
    bf16x8 af0 = *(const bf16x8*)&As[frow][ks0 + kq];                        \
    bf16x8 bf0 = *(const bf16x8*)&Bs[frow][ks0 + kq];                        \
    acc = __builtin_amdgcn_mfma_f32_32x32x16_bf16(af0, bf0, acc, 0, 0, 0);   \
    bf16x8 af1 = *(const bf16x8*)&As[frow][ks0 + 16 + kq];                   \
    bf16x8 bf1 = *(const bf16x8*)&Bs[frow][ks0 + 16 + kq];                   \
    acc = __builtin_amdgcn_mfma_f32_32x32x16_bf16(af1, bf1, acc, 0, 0, 0);   \
} while (0)

    LOAD_TILE(0, ra0, rb0);
    LOAD_TILE(1, ra1, rb1);

    #pragma unroll
    for (int kc2 = 0; kc2 < NIT; kc2 += 2) {
        // even iter: consumes set0, reloads set0 for kc2+2
        __syncthreads();
        STORE_TILE(ra0, rb0);
        __syncthreads();
        if (kc2 + 2 < NIT) LOAD_TILE(kc2 + 2, ra0, rb0);
        COMPUTE();
        // odd iter: consumes set1, reloads set1 for kc2+3
        __syncthreads();
        STORE_TILE(ra1, rb1);
        __syncthreads();
        if (kc2 + 3 < NIT) LOAD_TILE(kc2 + 3, ra1, rb1);
        COMPUTE();
    }
#undef LOAD_TILE
#undef STORE_TILE
#undef COMPUTE

    // ---- scatter accumulator to Red via verified C/D layout ----
    __syncthreads();   // As/Bs dead; all waves done computing
    #pragma unroll
    for (int r = 0; r < 16; ++r) {
        int row = (r & 3) + 8 * (r >> 2) + 4 * (lane >> 5);
        Red[wv][row][frow] = acc[r];
    }
    __syncthreads();

    // ---- epilogue: sum 4 wave-partials + bias + time_embed, f4 store ----
    {
        const int r  = tid >> 3;            // 0..31
        const int c0 = (tid & 7) * 4;       // 0..28
        float4 s0 = *(const float4*)&Red[0][r][c0];
        float4 s1 = *(const float4*)&Red[1][r][c0];
        float4 s2 = *(const float4*)&Red[2][r][c0];
        float4 s3 = *(const float4*)&Red[3][r][c0];
        float4 s;
        s.x = (s0.x + s1.x) + (s2.x + s3.x);
        s.y = (s0.y + s1.y) + (s2.y + s3.y);
        s.z = (s0.z + s1.z) + (s2.z + s3.z);
        s.w = (s0.w + s1.w) + (s2.w + s3.w);
        const int grow = row0 + r;
        const int cb   = col0 + c0;
        int t   = ws_times[grow];
        int tcl = t < (TVOCAB - 1) ? t : (TVOCAB - 1);
        const float4 bi = *(const float4*)(bias + cb);
        const float4 te = *(const float4*)(temb + (size_t)tcl * D_ + cb);
        s.x += bi.x + te.x; s.y += bi.y + te.y;
        s.z += bi.z + te.z; s.w += bi.w + te.w;
        *(float4*)(out + (size_t)grow * D_ + cb) = s;
    }
}

// ---------------------------------------------------------------------------
extern "C" void kernel_launch(void* const* d_in, const int* in_sizes, int n_in,
                              void* d_out, int out_size, void* d_ws, size_t ws_size,
                              hipStream_t stream)
{
    const float* h_seq = (const float*)d_in[0];
    const float* z     = (const float*)d_in[1];
    const float* ent   = (const float*)d_in[2];
    const float* W     = (const float*)d_in[3];
    const float* bias  = (const float*)d_in[4];
    const float* temb  = (const float*)d_in[5];

    float* out       = (float*)d_out;
    float* out_tape  = out;                                // 262144
    float* out_valid = out + (size_t)B_ * E_ * D_;         // 256
    float* out_times = out_valid + B_ * E_;                // 256

    // ws layout: [0] times (256 int) | [1KB] valid (256 int)
    int* ws_times = (int*)d_ws;
    int* ws_valid = (int*)((char*)d_ws + 1024);

    k_select<<<B_, 1024, 0, stream>>>(z, ws_times, ws_valid,
                                      out_valid, out_times);

    k_gemm<<<256, 256, 0, stream>>>(h_seq, ent, W, bias, temb,
                                    ws_times, ws_valid, out_tape);
}